// Round 13
// baseline (318.953 us; speedup 1.0000x reference)
//
#include <hip/hip_runtime.h>

#define LQ 8500

typedef _Float16 half8 __attribute__((ext_vector_type(8)));
typedef float f32x4 __attribute__((ext_vector_type(4)));

__device__ __forceinline__ unsigned short f2h(float f) {
    return __builtin_bit_cast(unsigned short, (_Float16)f);
}
__device__ __forceinline__ float hlo(unsigned w) {
    return (float)__builtin_bit_cast(_Float16, (unsigned short)(w & 0xffffu));
}
__device__ __forceinline__ float hhi(unsigned w) {
    return (float)__builtin_bit_cast(_Float16, (unsigned short)(w >> 16));
}
__device__ __forceinline__ unsigned pk2(float a, float b) {
    return (unsigned)f2h(a) | ((unsigned)f2h(b) << 16);
}

// async 16B global -> LDS (linear dest: wave-uniform base + lane*16)
__device__ __forceinline__ void gl_lds16(const unsigned short* gsrc, char* ldst) {
    __builtin_amdgcn_global_load_lds(
        (const __attribute__((address_space(1))) void*)gsrc,
        (__attribute__((address_space(3))) void*)ldst, 16, 0, 0);
}

// Inverse of the LDS read-swizzle swz(b)=b^(((b>>6)&7)<<4)  [verified in R12]:
// for a LINEAR gl_lds dest byte d, source logical byte b = d ^ (rm<<4),
// rm = (d6^d8) | (d7<<1) | (d8<<2).
__device__ __forceinline__ void inv_swz(int d, int& brow, int& bseg) {
    int b8 = (d >> 8) & 1;
    int rm = (((d >> 6) & 1) ^ b8) | (((d >> 7) & 1) << 1) | (b8 << 2);
    int b = d ^ (rm << 4);
    brow = b >> 6;
    bseg = (b >> 4) & 3;
}

// ---------------------------------------------------------------------------
// Kernel 0: weight prep. Wct[384][256] = [Woff|Watt]^T fp16, Wvt = Wval^T,
// Wot = Wout^T fp16, bcat[384] fp32.
// ---------------------------------------------------------------------------
__global__ __launch_bounds__(256) void prep_weights(const float* __restrict__ Woff,
                                                    const float* __restrict__ boff,
                                                    const float* __restrict__ Watt,
                                                    const float* __restrict__ batt,
                                                    const float* __restrict__ Wval,
                                                    const float* __restrict__ Wout,
                                                    unsigned short* __restrict__ Wct,
                                                    unsigned short* __restrict__ Wvt,
                                                    unsigned short* __restrict__ Wot,
                                                    float* __restrict__ bcat) {
    int idx = blockIdx.x * 256 + threadIdx.x;
    if (idx < 98304) {                       // Wct[j][k] = Wcat[k][j]
        int j = idx >> 8, k = idx & 255;
        float v = (j < 256) ? Woff[k * 256 + j] : Watt[k * 128 + (j - 256)];
        Wct[idx] = f2h(v);
    } else if (idx < 98304 + 65536) {        // Wvt[n][k] = Wval[k][n]
        int t = idx - 98304;
        int n = t >> 8, k = t & 255;
        Wvt[t] = f2h(Wval[k * 256 + n]);
    } else if (idx < 98304 + 131072) {       // Wot[n][k] = Wout[k][n]
        int t = idx - 98304 - 65536;
        int n = t >> 8, k = t & 255;
        Wot[t] = f2h(Wout[k * 256 + n]);
    } else if (idx < 98304 + 131072 + 384) {
        int j = idx - 98304 - 131072;
        bcat[j] = (j < 256) ? boff[j] : batt[j - 256];
    }
}

// ---------------------------------------------------------------------------
// Single-pass wide GEMM: C[M x N] = f16( A_f32[M x 256] @ Bt[N x 256]^T (+bias) )
// 512 threads = 8 waves (2 row x 4 col); block tile 128 x N (N = NJ*64).
// NJ=4 -> N=256 (Y, no bias). NJ=6 -> N=384 (P, +bias). A read from HBM ONCE.
// A staged via registers (fp32->f16 convert), B via global_load_lds (linear
// dest + inv_swz permuted source). Double-buffered, BK=32.
// ---------------------------------------------------------------------------
template <int NJ, int BIAS>
__global__ __launch_bounds__(512) void gemm_wide(const float* __restrict__ A,
                                                 const unsigned short* __restrict__ Bt,
                                                 const float* __restrict__ bias,
                                                 unsigned short* __restrict__ C,
                                                 int M) {
    const int BN = NJ * 64;                  // 256 or 384
    const int BUFSZ = 8192 + BN * 64;        // A(8KB) + B(BN*64B)
    const int NBCH = BN * 4;                 // B chunks of 16B per k-step
    const int NC = NBCH / 512;               // B chunks per thread (2 or 3)
    __shared__ char lds[2 * (8192 + NJ * 64 * 64)];

    const int tid = threadIdx.x;
    const int r0 = blockIdx.x * 128;
    const int wid = tid >> 6, lane = tid & 63;
    const int wr = (wid >> 2) * 64;          // 2 row-waves
    const int wc = (wid & 3) * (NJ * 16);    // 4 col-waves

    int browc[3], bsegc[3];
#pragma unroll
    for (int cc = 0; cc < NC; ++cc)
        inv_swz((cc * 512 + tid) << 4, browc[cc], bsegc[cc]);

    f32x4 acc[4][NJ] = {};
    uint4 ra;

    // A chunk: row = tid>>2 (0..127), seg = tid&3
#define LOADA(k0)                                                                   \
    {                                                                               \
        int row = tid >> 2, seg = tid & 3;                                          \
        uint4 va = {0, 0, 0, 0};                                                    \
        int ar = r0 + row;                                                          \
        if (ar < M) {                                                               \
            const float4* ap = reinterpret_cast<const float4*>(                     \
                A + (size_t)ar * 256 + (k0) + seg * 8);                             \
            float4 a = ap[0], b = ap[1];                                            \
            va.x = pk2(a.x, a.y); va.y = pk2(a.z, a.w);                             \
            va.z = pk2(b.x, b.y); va.w = pk2(b.z, b.w);                             \
        }                                                                           \
        ra = va;                                                                    \
    }

#define STOREA(bf)                                                                  \
    {                                                                               \
        int row = tid >> 2, seg = tid & 3;                                          \
        int byte = (row << 6) + (seg << 4);                                         \
        int swzb = byte ^ ((row & 7) << 4);                                         \
        *reinterpret_cast<uint4*>(lds + (bf) * BUFSZ + swzb) = ra;                  \
    }

#define LOADB(bf, k0)                                                               \
    {                                                                               \
        _Pragma("unroll")                                                           \
        for (int cc = 0; cc < NC; ++cc) {                                           \
            const unsigned short* gs =                                              \
                Bt + (size_t)browc[cc] * 256 + (k0) + bsegc[cc] * 8;                \
            gl_lds16(gs, lds + (bf) * BUFSZ + 8192 + cc * 8192 + wid * 1024);       \
        }                                                                           \
    }

    LOADA(0);
    LOADB(0, 0);
    STOREA(0);
    __syncthreads();

    for (int t = 0; t < 8; ++t) {
        if (t < 7) {
            LOADB((t + 1) & 1, (t + 1) * 32);
            LOADA((t + 1) * 32);
        }
        char* base = lds + (t & 1) * BUFSZ;
        half8 af[4], bfr[NJ];
#pragma unroll
        for (int i = 0; i < 4; ++i) {
            int rowA = wr + i * 16 + (lane & 15);
            int byteA = (rowA << 6) + ((lane >> 4) << 4);
            af[i] = *reinterpret_cast<const half8*>(base + (byteA ^ ((rowA & 7) << 4)));
        }
#pragma unroll
        for (int j = 0; j < NJ; ++j) {
            int rowB = wc + j * 16 + (lane & 15);
            int byteB = (rowB << 6) + ((lane >> 4) << 4);
            bfr[j] = *reinterpret_cast<const half8*>(base + 8192 + (byteB ^ ((rowB & 7) << 4)));
        }
#pragma unroll
        for (int i = 0; i < 4; ++i)
#pragma unroll
            for (int j = 0; j < NJ; ++j)
                acc[i][j] = __builtin_amdgcn_mfma_f32_16x16x32_f16(af[i], bfr[j], acc[i][j], 0, 0, 0);
        if (t < 7) STOREA((t + 1) & 1);
        __syncthreads();
    }

#pragma unroll
    for (int j = 0; j < NJ; ++j) {
        int col = wc + j * 16 + (lane & 15);
        float bv = BIAS ? bias[col] : 0.f;
#pragma unroll
        for (int i = 0; i < 4; ++i) {
#pragma unroll
            for (int r = 0; r < 4; ++r) {
                int row = r0 + wr + i * 16 + (lane >> 4) * 4 + r;
                if (row >= M) continue;
                C[(size_t)row * BN + col] = f2h(acc[i][j][r] + bv);
            }
        }
    }
#undef LOADA
#undef STOREA
#undef LOADB
}

// ---------------------------------------------------------------------------
// Out GEMM (R12-proven): out[M x 256] = O16 @ Wot^T + bout (fp32 out).
// Both A and B staged via global_load_lds (linear dest, permuted source).
// ---------------------------------------------------------------------------
__global__ __launch_bounds__(256) void gemm_out(const unsigned short* __restrict__ O16,
                                                const unsigned short* __restrict__ Wot,
                                                const float* __restrict__ bout,
                                                float* __restrict__ out) {
    __shared__ char lds[32768];
    const int tid = threadIdx.x;
    const int r0 = blockIdx.x * 128, c0 = blockIdx.y * 128;
    const int wid = tid >> 6, lane = tid & 63;
    const int wr = (wid >> 1) * 64, wc = (wid & 1) * 64;
    const int M = 8 * LQ;

    int browc[2], bsegc[2];
#pragma unroll
    for (int cc = 0; cc < 2; ++cc)
        inv_swz((cc * 256 + tid) << 4, browc[cc], bsegc[cc]);

    f32x4 acc[4][4] = {};

#define STAGE(bf, k0)                                                               \
    {                                                                               \
        _Pragma("unroll")                                                           \
        for (int cc = 0; cc < 2; ++cc) {                                            \
            char* lbase = lds + (bf) * 16384 + cc * 4096 + wid * 1024;              \
            int ar = r0 + browc[cc];                                                \
            if (ar < M)                                                             \
                gl_lds16(O16 + (size_t)ar * 256 + (k0) + bsegc[cc] * 8, lbase);     \
            gl_lds16(Wot + (size_t)(c0 + browc[cc]) * 256 + (k0) + bsegc[cc] * 8,   \
                     lbase + 8192);                                                 \
        }                                                                           \
    }

    STAGE(0, 0);
    __syncthreads();

    for (int t = 0; t < 8; ++t) {
        if (t < 7) STAGE((t + 1) & 1, (t + 1) * 32);
        char* base = lds + (t & 1) * 16384;
        half8 af[4], bfr[4];
#pragma unroll
        for (int i = 0; i < 4; ++i) {
            int rowA = wr + i * 16 + (lane & 15);
            int byteA = (rowA << 6) + ((lane >> 4) << 4);
            af[i] = *reinterpret_cast<const half8*>(base + (byteA ^ ((rowA & 7) << 4)));
            int rowB = wc + i * 16 + (lane & 15);
            int byteB = (rowB << 6) + ((lane >> 4) << 4);
            bfr[i] = *reinterpret_cast<const half8*>(base + 8192 + (byteB ^ ((rowB & 7) << 4)));
        }
#pragma unroll
        for (int i = 0; i < 4; ++i)
#pragma unroll
            for (int j = 0; j < 4; ++j)
                acc[i][j] = __builtin_amdgcn_mfma_f32_16x16x32_f16(af[i], bfr[j], acc[i][j], 0, 0, 0);
        __syncthreads();
    }

#pragma unroll
    for (int j = 0; j < 4; ++j) {
        int col = c0 + wc + j * 16 + (lane & 15);
        float bv = bout[col];
#pragma unroll
        for (int i = 0; i < 4; ++i) {
#pragma unroll
            for (int r = 0; r < 4; ++r) {
                int row = r0 + wr + i * 16 + (lane >> 4) * 4 + r;
                if (row >= M) continue;
                out[(size_t)row * 256 + col] = acc[i][j][r] + bv;
            }
        }
    }
#undef STAGE
}

// ---------------------------------------------------------------------------
// vsum: Vs plane [(g*8+m)][pos][32] = sum_{t2 in win(t1)} Y[(n*4+t2)*LQ+pos] + K*bval
// ---------------------------------------------------------------------------
__global__ __launch_bounds__(256) void vsum_kernel(const unsigned short* __restrict__ Y,
                                                   const float* __restrict__ bval,
                                                   unsigned short* __restrict__ Vs) {
    int plane = blockIdx.y;             // g*8 + m
    int g = plane >> 3, m = plane & 7;
    int t1 = g & 3, n = g >> 2;
    int f = blockIdx.x * 256 + threadIdx.x;
    if (f >= LQ * 4) return;
    int pos = f >> 2, c8 = (f & 3) * 8;
    float Kc = (t1 == 0 || t1 == 3) ? 2.f : 3.f;
    const float* bp = bval + m * 32 + c8;
    float acc[8];
#pragma unroll
    for (int j = 0; j < 8; ++j) acc[j] = Kc * bp[j];
    int t2a = t1 == 0 ? 0 : t1 - 1;
    int t2b = t1 == 3 ? 3 : t1 + 1;
    for (int t2 = t2a; t2 <= t2b; ++t2) {
        uint4 v = *reinterpret_cast<const uint4*>(
            Y + ((size_t)(n * 4 + t2) * LQ + pos) * 256 + m * 32 + c8);
        acc[0] += hlo(v.x); acc[1] += hhi(v.x);
        acc[2] += hlo(v.y); acc[3] += hhi(v.y);
        acc[4] += hlo(v.z); acc[5] += hhi(v.z);
        acc[6] += hlo(v.w); acc[7] += hhi(v.w);
    }
    uint4 o;
    o.x = pk2(acc[0], acc[1]); o.y = pk2(acc[2], acc[3]);
    o.z = pk2(acc[4], acc[5]); o.w = pk2(acc[6], acc[7]);
    *reinterpret_cast<uint4*>(Vs + ((size_t)plane * LQ + pos) * 32 + c8) = o;
}

// ---------------------------------------------------------------------------
// Sampler (R6/R11/R12-proven, byte-identical): fp32 acc, batched gather loads.
// Thread = (q, m, half): 16 channels. Block = 16 q x 8 m x 2 half of group g.
// ---------------------------------------------------------------------------
__global__ __launch_bounds__(256) void sample_kernel(const unsigned short* __restrict__ P,
                                                     const float* __restrict__ refp,
                                                     const unsigned short* __restrict__ Vs,
                                                     unsigned short* __restrict__ O16) {
    int tid = threadIdx.x, bid = blockIdx.x;
    int g = bid & 7;
    int q0 = (bid >> 3) * 16;
    int ql = tid >> 4, m = (tid >> 1) & 7, h = tid & 1;
    int q = q0 + ql;
    if (q >= LQ) return;

    const size_t qrow = (size_t)g * LQ + q;

    unsigned ow[16];
    {
        const uint4* po = reinterpret_cast<const uint4*>(P + qrow * 384 + m * 32);
        uint4 a = po[0], b = po[1], c = po[2], d = po[3];
        ow[0] = a.x; ow[1] = a.y; ow[2] = a.z; ow[3] = a.w;
        ow[4] = b.x; ow[5] = b.y; ow[6] = b.z; ow[7] = b.w;
        ow[8] = c.x; ow[9] = c.y; ow[10] = c.z; ow[11] = c.w;
        ow[12] = d.x; ow[13] = d.y; ow[14] = d.z; ow[15] = d.w;
    }
    float wgt[16];
    {
        const uint4* pa = reinterpret_cast<const uint4*>(P + qrow * 384 + 256 + m * 16);
        uint4 a = pa[0], b = pa[1];
        unsigned aw[8] = {a.x, a.y, a.z, a.w, b.x, b.y, b.z, b.w};
#pragma unroll
        for (int j = 0; j < 8; ++j) {
            wgt[j * 2 + 0] = hlo(aw[j]);
            wgt[j * 2 + 1] = hhi(aw[j]);
        }
        float mx = -1e30f;
#pragma unroll
        for (int j = 0; j < 16; ++j) mx = fmaxf(mx, wgt[j]);
        float s = 0.f;
#pragma unroll
        for (int j = 0; j < 16; ++j) { wgt[j] = __expf(wgt[j] - mx); s += wgt[j]; }
        int t1 = g & 3;
        float Kc = (t1 == 0 || t1 == 3) ? 2.f : 3.f;
        float inv = 1.f / (s * Kc);
#pragma unroll
        for (int j = 0; j < 16; ++j) wgt[j] *= inv;
    }

    float rx[4], ry[4];
    {
        const float4* rp = reinterpret_cast<const float4*>(refp + qrow * 8);
        float4 r0 = rp[0], r1 = rp[1];
        rx[0] = r0.x; ry[0] = r0.y; rx[1] = r0.z; ry[1] = r0.w;
        rx[2] = r1.x; ry[2] = r1.y; rx[3] = r1.z; ry[3] = r1.w;
    }

    float acc[16];
#pragma unroll
    for (int d = 0; d < 16; ++d) acc[d] = 0.f;

    const unsigned short* vplane = Vs + (size_t)(g * 8 + m) * (LQ * 32) + h * 16;

#pragma unroll 4
    for (int p = 0; p < 16; ++p) {
        const int l = p >> 2;
        const int Wl = 80 >> l;
        const int start = (l == 0) ? 0 : (l == 1) ? 6400 : (l == 2) ? 8000 : 8400;
        const float Wlf = (float)Wl;

        float x = fmaf(rx[l], Wlf, hlo(ow[p])) - 0.5f;
        float y = fmaf(ry[l], Wlf, hhi(ow[p])) - 0.5f;
        float w = wgt[p];

        float xf = floorf(x), yf = floorf(y);
        int x0 = (int)xf, y0 = (int)yf;
        float wx1 = x - xf, wy1 = y - yf;

        int xb = min(max(x0, 0), Wl - 2);
        float wl = (x0 == xb) ? 1.f - wx1 : ((x0 + 1 == xb) ? wx1 : 0.f);
        float wr = (x0 == xb) ? wx1 : ((x0 - 1 == xb) ? 1.f - wx1 : 0.f);

        int yc0 = min(max(y0, 0), Wl - 1);
        float cw0 = (y0 >= 0 && y0 < Wl) ? (1.f - wy1) * w : 0.f;
        int y1i = y0 + 1;
        int yc1 = min(max(y1i, 0), Wl - 1);
        float cw1 = (y1i >= 0 && y1i < Wl) ? wy1 * w : 0.f;

        const uint4* p0 = reinterpret_cast<const uint4*>(
            vplane + (size_t)(start + yc0 * Wl + xb) * 32);
        const uint4* p1 = reinterpret_cast<const uint4*>(
            vplane + (size_t)(start + yc1 * Wl + xb) * 32);
        uint4 L0a = p0[0], L0b = p0[1], R0a = p0[4], R0b = p0[5];
        uint4 L1a = p1[0], L1b = p1[1], R1a = p1[4], R1b = p1[5];

        float c0l = cw0 * wl, c0r = cw0 * wr;
        float c1l = cw1 * wl, c1r = cw1 * wr;

        acc[0]  += c0l * hlo(L0a.x) + c0r * hlo(R0a.x) + c1l * hlo(L1a.x) + c1r * hlo(R1a.x);
        acc[1]  += c0l * hhi(L0a.x) + c0r * hhi(R0a.x) + c1l * hhi(L1a.x) + c1r * hhi(R1a.x);
        acc[2]  += c0l * hlo(L0a.y) + c0r * hlo(R0a.y) + c1l * hlo(L1a.y) + c1r * hlo(R1a.y);
        acc[3]  += c0l * hhi(L0a.y) + c0r * hhi(R0a.y) + c1l * hhi(L1a.y) + c1r * hhi(R1a.y);
        acc[4]  += c0l * hlo(L0a.z) + c0r * hlo(R0a.z) + c1l * hlo(L1a.z) + c1r * hlo(R1a.z);
        acc[5]  += c0l * hhi(L0a.z) + c0r * hhi(R0a.z) + c1l * hhi(L1a.z) + c1r * hhi(R1a.z);
        acc[6]  += c0l * hlo(L0a.w) + c0r * hlo(R0a.w) + c1l * hlo(L1a.w) + c1r * hlo(R1a.w);
        acc[7]  += c0l * hhi(L0a.w) + c0r * hhi(R0a.w) + c1l * hhi(L1a.w) + c1r * hhi(R1a.w);
        acc[8]  += c0l * hlo(L0b.x) + c0r * hlo(R0b.x) + c1l * hlo(L1b.x) + c1r * hlo(R1b.x);
        acc[9]  += c0l * hhi(L0b.x) + c0r * hhi(R0b.x) + c1l * hhi(L1b.x) + c1r * hhi(R1b.x);
        acc[10] += c0l * hlo(L0b.y) + c0r * hlo(R0b.y) + c1l * hlo(L1b.y) + c1r * hlo(R1b.y);
        acc[11] += c0l * hhi(L0b.y) + c0r * hhi(R0b.y) + c1l * hhi(L1b.y) + c1r * hhi(R1b.y);
        acc[12] += c0l * hlo(L0b.z) + c0r * hlo(R0b.z) + c1l * hlo(L1b.z) + c1r * hlo(R1b.z);
        acc[13] += c0l * hhi(L0b.z) + c0r * hhi(R0b.z) + c1l * hhi(L1b.z) + c1r * hhi(R1b.z);
        acc[14] += c0l * hlo(L0b.w) + c0r * hlo(R0b.w) + c1l * hlo(L1b.w) + c1r * hlo(R1b.w);
        acc[15] += c0l * hhi(L0b.w) + c0r * hhi(R0b.w) + c1l * hhi(L1b.w) + c1r * hhi(R1b.w);
    }

    unsigned short* op = O16 + qrow * 256 + m * 32 + h * 16;
    uint4 o0, o1;
    o0.x = pk2(acc[0], acc[1]);   o0.y = pk2(acc[2], acc[3]);
    o0.z = pk2(acc[4], acc[5]);   o0.w = pk2(acc[6], acc[7]);
    o1.x = pk2(acc[8], acc[9]);   o1.y = pk2(acc[10], acc[11]);
    o1.z = pk2(acc[12], acc[13]); o1.w = pk2(acc[14], acc[15]);
    reinterpret_cast<uint4*>(op)[0] = o0;
    reinterpret_cast<uint4*>(op)[1] = o1;
}

// ---------------------------------------------------------------------------
extern "C" void kernel_launch(void* const* d_in, const int* in_sizes, int n_in,
                              void* d_out, int out_size, void* d_ws, size_t ws_size,
                              hipStream_t stream) {
    const float* query = (const float*)d_in[0];
    const float* refp  = (const float*)d_in[1];
    const float* inp   = (const float*)d_in[2];
    const float* Woff = (const float*)d_in[5];
    const float* boff = (const float*)d_in[6];
    const float* Watt = (const float*)d_in[7];
    const float* batt = (const float*)d_in[8];
    const float* Wval = (const float*)d_in[9];
    const float* bval = (const float*)d_in[10];
    const float* Wout = (const float*)d_in[11];
    const float* bout = (const float*)d_in[12];
    float* out = (float*)d_out;

    // workspace layout (bytes):
    //   Y/O16 f16 [68000][256]          @ 0            (34,816,000)  (Y dead after vsum)
    //   Vs    f16 [64 planes][8500][32] @ 34,816,000   (34,816,000)
    //   P     f16 [68000][384]          @ 69,632,000   (52,224,000)
    //   Wct   f16 [384][256]            @ 121,856,000  (196,608)
    //   Wvt   f16 [256][256]            @ 122,052,608  (131,072)
    //   Wot   f16 [256][256]            @ 122,183,680  (131,072)
    //   bcat  f32 [384]                 @ 122,314,752  (1,536)
    char* base = (char*)d_ws;
    unsigned short* Y    = (unsigned short*)base;
    unsigned short* O16  = (unsigned short*)base;            // alias (Y dead)
    unsigned short* Vs   = (unsigned short*)(base + 34816000);
    unsigned short* P    = (unsigned short*)(base + 69632000);
    unsigned short* Wct  = (unsigned short*)(base + 121856000);
    unsigned short* Wvt  = (unsigned short*)(base + 122052608);
    unsigned short* Wot  = (unsigned short*)(base + 122183680);
    float* bcat          = (float*)(base + 122314752);

    const int RT = (8 * LQ + 127) / 128;   // 532 row tiles

    // 0) weight prep
    prep_weights<<<dim3(898), 256, 0, stream>>>(Woff, boff, Watt, batt, Wval, Wout,
                                                Wct, Wvt, Wot, bcat);

    // 1) Y = f16(inp @ Wval), single-pass N=256 (A read once)
    gemm_wide<4, 0><<<dim3(RT), 512, 0, stream>>>(inp, Wvt, bcat, Y, 8 * LQ);

    // 2) P = f16(query @ Wcat + bcat), single-pass N=384 (A read once)
    gemm_wide<6, 1><<<dim3(RT), 512, 0, stream>>>(query, Wct, bcat, P, 8 * LQ);

    // 3) Vs planes = sum_{t2} Y + K(t1)*bval
    vsum_kernel<<<dim3((LQ * 4 + 255) / 256, 64), 256, 0, stream>>>(Y, bval, Vs);

    // 4) sampler -> O16 (aliases Y, dead after vsum)
    sample_kernel<<<dim3(((LQ + 15) / 16) * 8), 256, 0, stream>>>(P, refp, Vs, O16);

    // 5) d_out = O16 @ Wout + bout (fp32)
    gemm_out<<<dim3(RT, 2), 256, 0, stream>>>(O16, Wot, bout, out);
}

// Round 14
// 309.611 us; speedup vs baseline: 1.0302x; 1.0302x over previous
//
#include <hip/hip_runtime.h>

#define LQ 8500

typedef _Float16 half8 __attribute__((ext_vector_type(8)));
typedef float f32x4 __attribute__((ext_vector_type(4)));

__device__ __forceinline__ unsigned short f2h(float f) {
    return __builtin_bit_cast(unsigned short, (_Float16)f);
}
__device__ __forceinline__ float hlo(unsigned w) {
    return (float)__builtin_bit_cast(_Float16, (unsigned short)(w & 0xffffu));
}
__device__ __forceinline__ float hhi(unsigned w) {
    return (float)__builtin_bit_cast(_Float16, (unsigned short)(w >> 16));
}
__device__ __forceinline__ unsigned pk2(float a, float b) {
    return (unsigned)f2h(a) | ((unsigned)f2h(b) << 16);
}

// async 16B global -> LDS (linear dest: wave-uniform base + lane*16)
__device__ __forceinline__ void gl_lds16(const unsigned short* gsrc, char* ldst) {
    __builtin_amdgcn_global_load_lds(
        (const __attribute__((address_space(1))) void*)gsrc,
        (__attribute__((address_space(3))) void*)ldst, 16, 0, 0);
}

// ---------------------------------------------------------------------------
// Kernel 0: weight prep. Wct[384][256] = [Woff|Watt]^T fp16, Wvt = Wval^T,
// Wot = Wout^T fp16, bcat[384] fp32.
// ---------------------------------------------------------------------------
__global__ __launch_bounds__(256) void prep_weights(const float* __restrict__ Woff,
                                                    const float* __restrict__ boff,
                                                    const float* __restrict__ Watt,
                                                    const float* __restrict__ batt,
                                                    const float* __restrict__ Wval,
                                                    const float* __restrict__ Wout,
                                                    unsigned short* __restrict__ Wct,
                                                    unsigned short* __restrict__ Wvt,
                                                    unsigned short* __restrict__ Wot,
                                                    float* __restrict__ bcat) {
    int idx = blockIdx.x * 256 + threadIdx.x;
    if (idx < 98304) {                       // Wct[j][k] = Wcat[k][j]
        int j = idx >> 8, k = idx & 255;
        float v = (j < 256) ? Woff[k * 256 + j] : Watt[k * 128 + (j - 256)];
        Wct[idx] = f2h(v);
    } else if (idx < 98304 + 65536) {        // Wvt[n][k] = Wval[k][n]
        int t = idx - 98304;
        int n = t >> 8, k = t & 255;
        Wvt[t] = f2h(Wval[k * 256 + n]);
    } else if (idx < 98304 + 131072) {       // Wot[n][k] = Wout[k][n]
        int t = idx - 98304 - 65536;
        int n = t >> 8, k = t & 255;
        Wot[t] = f2h(Wout[k * 256 + n]);
    } else if (idx < 98304 + 131072 + 384) {
        int j = idx - 98304 - 131072;
        bcat[j] = (j < 256) ? boff[j] : batt[j - 256];
    }
}

// ---------------------------------------------------------------------------
// Swizzle involution source-permute: LDS read uses addr swz(b)=b^((b>>6&7)<<4).
// For a LINEAR gl_lds dest byte d, the source logical byte is b = inv(d):
//   b = d ^ (rm<<4),  rm = (d6^d8) | (d7<<1) | (d8<<2).   [verified in R12]
// ---------------------------------------------------------------------------
__device__ __forceinline__ void inv_swz(int d, int& brow, int& bseg) {
    int b8 = (d >> 8) & 1;
    int rm = (((d >> 6) & 1) ^ b8) | (((d >> 7) & 1) << 1) | (b8 << 2);
    int b = d ^ (rm << 4);
    brow = b >> 6;
    bseg = (b >> 4) & 3;
}

// ---------------------------------------------------------------------------
// Combined Y/P MFMA GEMM (fp32 A converted in staging; B via global_load_lds).
// grid = (RT, 5): yb<2 -> Y = inp @ Wvt (fp16, N=256, no bias)
//                 yb>=2 -> P = query @ Wct + bcat (fp16, N=384)
// 128x128 tile, BK=32, double-buffered, 4 waves.
// ---------------------------------------------------------------------------
__global__ __launch_bounds__(256) void gemm_yp(const float* __restrict__ inp,
                                               const float* __restrict__ query,
                                               const unsigned short* __restrict__ Wvt,
                                               const unsigned short* __restrict__ Wct,
                                               const float* __restrict__ bcat,
                                               unsigned short* __restrict__ Yo,
                                               unsigned short* __restrict__ Po) {
    __shared__ char lds[32768];   // buf b: A @ b*16384, B @ b*16384+8192
    const int tid = threadIdx.x;
    const int r0 = blockIdx.x * 128;
    const int yb = blockIdx.y;
    const bool isY = yb < 2;
    const int c0 = isY ? yb * 128 : (yb - 2) * 128;
    const float* A = isY ? inp : query;
    const unsigned short* Bt = isY ? Wvt : Wct;
    const int wid = tid >> 6, lane = tid & 63;
    const int wr = (wid >> 1) * 64, wc = (wid & 1) * 64;
    const int M = 8 * LQ;

    int browc[2], bsegc[2];
#pragma unroll
    for (int cc = 0; cc < 2; ++cc)
        inv_swz((cc * 256 + tid) << 4, browc[cc], bsegc[cc]);

    f32x4 acc[4][4] = {};
    uint4 ra[2];

#define LOADA(k0)                                                                   \
    {                                                                               \
        _Pragma("unroll")                                                           \
        for (int cc = 0; cc < 2; ++cc) {                                            \
            int ch = cc * 256 + tid;                                               \
            int row = ch >> 2, seg = ch & 3;                                        \
            uint4 va = {0, 0, 0, 0};                                               \
            int ar = r0 + row;                                                      \
            if (ar < M) {                                                           \
                const float4* ap = reinterpret_cast<const float4*>(                 \
                    A + (size_t)ar * 256 + (k0) + seg * 8);                         \
                float4 a = ap[0], b = ap[1];                                        \
                va.x = pk2(a.x, a.y); va.y = pk2(a.z, a.w);                         \
                va.z = pk2(b.x, b.y); va.w = pk2(b.z, b.w);                         \
            }                                                                       \
            ra[cc] = va;                                                            \
        }                                                                           \
    }

#define STOREA(bf)                                                                  \
    {                                                                               \
        _Pragma("unroll")                                                           \
        for (int cc = 0; cc < 2; ++cc) {                                            \
            int ch = cc * 256 + tid;                                               \
            int row = ch >> 2, seg = ch & 3;                                        \
            int byte = (row << 6) + (seg << 4);                                     \
            int swzb = byte ^ ((row & 7) << 4);                                     \
            *reinterpret_cast<uint4*>(lds + (bf) * 16384 + swzb) = ra[cc];          \
        }                                                                           \
    }

#define LOADB(bf, k0)                                                               \
    {                                                                               \
        _Pragma("unroll")                                                           \
        for (int cc = 0; cc < 2; ++cc) {                                            \
            const unsigned short* gs =                                              \
                Bt + (size_t)(c0 + browc[cc]) * 256 + (k0) + bsegc[cc] * 8;         \
            gl_lds16(gs, lds + (bf) * 16384 + 8192 + cc * 4096 + wid * 1024);       \
        }                                                                           \
    }

    LOADA(0);
    LOADB(0, 0);
    STOREA(0);
    __syncthreads();

    for (int t = 0; t < 8; ++t) {
        if (t < 7) {
            LOADB((t + 1) & 1, (t + 1) * 32);
            LOADA((t + 1) * 32);
        }
        char* base = lds + (t & 1) * 16384;
        half8 af[4], bfr[4];
#pragma unroll
        for (int i = 0; i < 4; ++i) {
            int rowA = wr + i * 16 + (lane & 15);
            int byteA = (rowA << 6) + ((lane >> 4) << 4);
            af[i] = *reinterpret_cast<const half8*>(base + (byteA ^ ((rowA & 7) << 4)));
            int rowB = wc + i * 16 + (lane & 15);
            int byteB = (rowB << 6) + ((lane >> 4) << 4);
            bfr[i] = *reinterpret_cast<const half8*>(base + 8192 + (byteB ^ ((rowB & 7) << 4)));
        }
#pragma unroll
        for (int i = 0; i < 4; ++i)
#pragma unroll
            for (int j = 0; j < 4; ++j)
                acc[i][j] = __builtin_amdgcn_mfma_f32_16x16x32_f16(af[i], bfr[j], acc[i][j], 0, 0, 0);
        if (t < 7) STOREA((t + 1) & 1);
        __syncthreads();
    }

#pragma unroll
    for (int j = 0; j < 4; ++j) {
        int col = c0 + wc + j * 16 + (lane & 15);
        float bv = isY ? 0.f : bcat[col];
#pragma unroll
        for (int i = 0; i < 4; ++i) {
#pragma unroll
            for (int r = 0; r < 4; ++r) {
                int row = r0 + wr + i * 16 + (lane >> 4) * 4 + r;
                if (row >= M) continue;
                float v = acc[i][j][r] + bv;
                if (isY) Yo[(size_t)row * 256 + col] = f2h(v);
                else     Po[(size_t)row * 384 + col] = f2h(v);
            }
        }
    }
#undef LOADA
#undef STOREA
#undef LOADB
}

// ---------------------------------------------------------------------------
// Out GEMM: out[M x 256] = O16 @ Wot^T + bout (fp32 out).
// Both A and B staged via global_load_lds (linear dest, permuted source).
// ---------------------------------------------------------------------------
__global__ __launch_bounds__(256) void gemm_out(const unsigned short* __restrict__ O16,
                                                const unsigned short* __restrict__ Wot,
                                                const float* __restrict__ bout,
                                                float* __restrict__ out) {
    __shared__ char lds[32768];
    const int tid = threadIdx.x;
    const int r0 = blockIdx.x * 128, c0 = blockIdx.y * 128;
    const int wid = tid >> 6, lane = tid & 63;
    const int wr = (wid >> 1) * 64, wc = (wid & 1) * 64;
    const int M = 8 * LQ;

    int browc[2], bsegc[2];
#pragma unroll
    for (int cc = 0; cc < 2; ++cc)
        inv_swz((cc * 256 + tid) << 4, browc[cc], bsegc[cc]);

    f32x4 acc[4][4] = {};

#define STAGE(bf, k0)                                                               \
    {                                                                               \
        _Pragma("unroll")                                                           \
        for (int cc = 0; cc < 2; ++cc) {                                            \
            char* lbase = lds + (bf) * 16384 + cc * 4096 + wid * 1024;              \
            int ar = r0 + browc[cc];                                                \
            if (ar < M)                                                             \
                gl_lds16(O16 + (size_t)ar * 256 + (k0) + bsegc[cc] * 8, lbase);     \
            gl_lds16(Wot + (size_t)(c0 + browc[cc]) * 256 + (k0) + bsegc[cc] * 8,   \
                     lbase + 8192);                                                 \
        }                                                                           \
    }

    STAGE(0, 0);
    __syncthreads();

    for (int t = 0; t < 8; ++t) {
        if (t < 7) STAGE((t + 1) & 1, (t + 1) * 32);
        char* base = lds + (t & 1) * 16384;
        half8 af[4], bfr[4];
#pragma unroll
        for (int i = 0; i < 4; ++i) {
            int rowA = wr + i * 16 + (lane & 15);
            int byteA = (rowA << 6) + ((lane >> 4) << 4);
            af[i] = *reinterpret_cast<const half8*>(base + (byteA ^ ((rowA & 7) << 4)));
            int rowB = wc + i * 16 + (lane & 15);
            int byteB = (rowB << 6) + ((lane >> 4) << 4);
            bfr[i] = *reinterpret_cast<const half8*>(base + 8192 + (byteB ^ ((rowB & 7) << 4)));
        }
#pragma unroll
        for (int i = 0; i < 4; ++i)
#pragma unroll
            for (int j = 0; j < 4; ++j)
                acc[i][j] = __builtin_amdgcn_mfma_f32_16x16x32_f16(af[i], bfr[j], acc[i][j], 0, 0, 0);
        __syncthreads();
    }

#pragma unroll
    for (int j = 0; j < 4; ++j) {
        int col = c0 + wc + j * 16 + (lane & 15);
        float bv = bout[col];
#pragma unroll
        for (int i = 0; i < 4; ++i) {
#pragma unroll
            for (int r = 0; r < 4; ++r) {
                int row = r0 + wr + i * 16 + (lane >> 4) * 4 + r;
                if (row >= M) continue;
                out[(size_t)row * 256 + col] = acc[i][j][r] + bv;
            }
        }
    }
#undef STAGE
}

// ---------------------------------------------------------------------------
// vsum: Vs plane [(g*8+m)][pos][32] = sum_{t2 in win(t1)} Y[(n*4+t2)*LQ+pos] + K*bval
// ---------------------------------------------------------------------------
__global__ __launch_bounds__(256) void vsum_kernel(const unsigned short* __restrict__ Y,
                                                   const float* __restrict__ bval,
                                                   unsigned short* __restrict__ Vs) {
    int plane = blockIdx.y;             // g*8 + m
    int g = plane >> 3, m = plane & 7;
    int t1 = g & 3, n = g >> 2;
    int f = blockIdx.x * 256 + threadIdx.x;
    if (f >= LQ * 4) return;
    int pos = f >> 2, c8 = (f & 3) * 8;
    float Kc = (t1 == 0 || t1 == 3) ? 2.f : 3.f;
    const float* bp = bval + m * 32 + c8;
    float acc[8];
#pragma unroll
    for (int j = 0; j < 8; ++j) acc[j] = Kc * bp[j];
    int t2a = t1 == 0 ? 0 : t1 - 1;
    int t2b = t1 == 3 ? 3 : t1 + 1;
    for (int t2 = t2a; t2 <= t2b; ++t2) {
        uint4 v = *reinterpret_cast<const uint4*>(
            Y + ((size_t)(n * 4 + t2) * LQ + pos) * 256 + m * 32 + c8);
        acc[0] += hlo(v.x); acc[1] += hhi(v.x);
        acc[2] += hlo(v.y); acc[3] += hhi(v.y);
        acc[4] += hlo(v.z); acc[5] += hhi(v.z);
        acc[6] += hlo(v.w); acc[7] += hhi(v.w);
    }
    uint4 o;
    o.x = pk2(acc[0], acc[1]); o.y = pk2(acc[2], acc[3]);
    o.z = pk2(acc[4], acc[5]); o.w = pk2(acc[6], acc[7]);
    *reinterpret_cast<uint4*>(Vs + ((size_t)plane * LQ + pos) * 32 + c8) = o;
}

// ---------------------------------------------------------------------------
// Sampler (R6/R11/R12-proven, byte-identical): fp32 acc, batched gather loads.
// Thread = (q, m, half): 16 channels. Block = 16 q x 8 m x 2 half of group g.
// ---------------------------------------------------------------------------
__global__ __launch_bounds__(256) void sample_kernel(const unsigned short* __restrict__ P,
                                                     const float* __restrict__ refp,
                                                     const unsigned short* __restrict__ Vs,
                                                     unsigned short* __restrict__ O16) {
    int tid = threadIdx.x, bid = blockIdx.x;
    int g = bid & 7;
    int q0 = (bid >> 3) * 16;
    int ql = tid >> 4, m = (tid >> 1) & 7, h = tid & 1;
    int q = q0 + ql;
    if (q >= LQ) return;

    const size_t qrow = (size_t)g * LQ + q;

    unsigned ow[16];
    {
        const uint4* po = reinterpret_cast<const uint4*>(P + qrow * 384 + m * 32);
        uint4 a = po[0], b = po[1], c = po[2], d = po[3];
        ow[0] = a.x; ow[1] = a.y; ow[2] = a.z; ow[3] = a.w;
        ow[4] = b.x; ow[5] = b.y; ow[6] = b.z; ow[7] = b.w;
        ow[8] = c.x; ow[9] = c.y; ow[10] = c.z; ow[11] = c.w;
        ow[12] = d.x; ow[13] = d.y; ow[14] = d.z; ow[15] = d.w;
    }
    float wgt[16];
    {
        const uint4* pa = reinterpret_cast<const uint4*>(P + qrow * 384 + 256 + m * 16);
        uint4 a = pa[0], b = pa[1];
        unsigned aw[8] = {a.x, a.y, a.z, a.w, b.x, b.y, b.z, b.w};
#pragma unroll
        for (int j = 0; j < 8; ++j) {
            wgt[j * 2 + 0] = hlo(aw[j]);
            wgt[j * 2 + 1] = hhi(aw[j]);
        }
        float mx = -1e30f;
#pragma unroll
        for (int j = 0; j < 16; ++j) mx = fmaxf(mx, wgt[j]);
        float s = 0.f;
#pragma unroll
        for (int j = 0; j < 16; ++j) { wgt[j] = __expf(wgt[j] - mx); s += wgt[j]; }
        int t1 = g & 3;
        float Kc = (t1 == 0 || t1 == 3) ? 2.f : 3.f;
        float inv = 1.f / (s * Kc);
#pragma unroll
        for (int j = 0; j < 16; ++j) wgt[j] *= inv;
    }

    float rx[4], ry[4];
    {
        const float4* rp = reinterpret_cast<const float4*>(refp + qrow * 8);
        float4 r0 = rp[0], r1 = rp[1];
        rx[0] = r0.x; ry[0] = r0.y; rx[1] = r0.z; ry[1] = r0.w;
        rx[2] = r1.x; ry[2] = r1.y; rx[3] = r1.z; ry[3] = r1.w;
    }

    float acc[16];
#pragma unroll
    for (int d = 0; d < 16; ++d) acc[d] = 0.f;

    const unsigned short* vplane = Vs + (size_t)(g * 8 + m) * (LQ * 32) + h * 16;

#pragma unroll 4
    for (int p = 0; p < 16; ++p) {
        const int l = p >> 2;
        const int Wl = 80 >> l;
        const int start = (l == 0) ? 0 : (l == 1) ? 6400 : (l == 2) ? 8000 : 8400;
        const float Wlf = (float)Wl;

        float x = fmaf(rx[l], Wlf, hlo(ow[p])) - 0.5f;
        float y = fmaf(ry[l], Wlf, hhi(ow[p])) - 0.5f;
        float w = wgt[p];

        float xf = floorf(x), yf = floorf(y);
        int x0 = (int)xf, y0 = (int)yf;
        float wx1 = x - xf, wy1 = y - yf;

        int xb = min(max(x0, 0), Wl - 2);
        float wl = (x0 == xb) ? 1.f - wx1 : ((x0 + 1 == xb) ? wx1 : 0.f);
        float wr = (x0 == xb) ? wx1 : ((x0 - 1 == xb) ? 1.f - wx1 : 0.f);

        int yc0 = min(max(y0, 0), Wl - 1);
        float cw0 = (y0 >= 0 && y0 < Wl) ? (1.f - wy1) * w : 0.f;
        int y1i = y0 + 1;
        int yc1 = min(max(y1i, 0), Wl - 1);
        float cw1 = (y1i >= 0 && y1i < Wl) ? wy1 * w : 0.f;

        const uint4* p0 = reinterpret_cast<const uint4*>(
            vplane + (size_t)(start + yc0 * Wl + xb) * 32);
        const uint4* p1 = reinterpret_cast<const uint4*>(
            vplane + (size_t)(start + yc1 * Wl + xb) * 32);
        uint4 L0a = p0[0], L0b = p0[1], R0a = p0[4], R0b = p0[5];
        uint4 L1a = p1[0], L1b = p1[1], R1a = p1[4], R1b = p1[5];

        float c0l = cw0 * wl, c0r = cw0 * wr;
        float c1l = cw1 * wl, c1r = cw1 * wr;

        acc[0]  += c0l * hlo(L0a.x) + c0r * hlo(R0a.x) + c1l * hlo(L1a.x) + c1r * hlo(R1a.x);
        acc[1]  += c0l * hhi(L0a.x) + c0r * hhi(R0a.x) + c1l * hhi(L1a.x) + c1r * hhi(R1a.x);
        acc[2]  += c0l * hlo(L0a.y) + c0r * hlo(R0a.y) + c1l * hlo(L1a.y) + c1r * hlo(R1a.y);
        acc[3]  += c0l * hhi(L0a.y) + c0r * hhi(R0a.y) + c1l * hhi(L1a.y) + c1r * hhi(R1a.y);
        acc[4]  += c0l * hlo(L0a.z) + c0r * hlo(R0a.z) + c1l * hlo(L1a.z) + c1r * hlo(R1a.z);
        acc[5]  += c0l * hhi(L0a.z) + c0r * hhi(R0a.z) + c1l * hhi(L1a.z) + c1r * hhi(R1a.z);
        acc[6]  += c0l * hlo(L0a.w) + c0r * hlo(R0a.w) + c1l * hlo(L1a.w) + c1r * hlo(R1a.w);
        acc[7]  += c0l * hhi(L0a.w) + c0r * hhi(R0a.w) + c1l * hhi(L1a.w) + c1r * hhi(R1a.w);
        acc[8]  += c0l * hlo(L0b.x) + c0r * hlo(R0b.x) + c1l * hlo(L1b.x) + c1r * hlo(R1b.x);
        acc[9]  += c0l * hhi(L0b.x) + c0r * hhi(R0b.x) + c1l * hhi(L1b.x) + c1r * hhi(R1b.x);
        acc[10] += c0l * hlo(L0b.y) + c0r * hlo(R0b.y) + c1l * hlo(L1b.y) + c1r * hlo(R1b.y);
        acc[11] += c0l * hhi(L0b.y) + c0r * hhi(R0b.y) + c1l * hhi(L1b.y) + c1r * hhi(R1b.y);
        acc[12] += c0l * hlo(L0b.z) + c0r * hlo(R0b.z) + c1l * hlo(L1b.z) + c1r * hlo(R1b.z);
        acc[13] += c0l * hhi(L0b.z) + c0r * hhi(R0b.z) + c1l * hhi(L1b.z) + c1r * hhi(R1b.z);
        acc[14] += c0l * hlo(L0b.w) + c0r * hlo(R0b.w) + c1l * hlo(L1b.w) + c1r * hlo(R1b.w);
        acc[15] += c0l * hhi(L0b.w) + c0r * hhi(R0b.w) + c1l * hhi(L1b.w) + c1r * hhi(R1b.w);
    }

    unsigned short* op = O16 + qrow * 256 + m * 32 + h * 16;
    uint4 o0, o1;
    o0.x = pk2(acc[0], acc[1]);   o0.y = pk2(acc[2], acc[3]);
    o0.z = pk2(acc[4], acc[5]);   o0.w = pk2(acc[6], acc[7]);
    o1.x = pk2(acc[8], acc[9]);   o1.y = pk2(acc[10], acc[11]);
    o1.z = pk2(acc[12], acc[13]); o1.w = pk2(acc[14], acc[15]);
    reinterpret_cast<uint4*>(op)[0] = o0;
    reinterpret_cast<uint4*>(op)[1] = o1;
}

// ---------------------------------------------------------------------------
extern "C" void kernel_launch(void* const* d_in, const int* in_sizes, int n_in,
                              void* d_out, int out_size, void* d_ws, size_t ws_size,
                              hipStream_t stream) {
    const float* query = (const float*)d_in[0];
    const float* refp  = (const float*)d_in[1];
    const float* inp   = (const float*)d_in[2];
    const float* Woff = (const float*)d_in[5];
    const float* boff = (const float*)d_in[6];
    const float* Watt = (const float*)d_in[7];
    const float* batt = (const float*)d_in[8];
    const float* Wval = (const float*)d_in[9];
    const float* bval = (const float*)d_in[10];
    const float* Wout = (const float*)d_in[11];
    const float* bout = (const float*)d_in[12];
    float* out = (float*)d_out;

    // workspace layout (bytes):
    //   Y/O16 f16 [68000][256]          @ 0            (34,816,000)  (Y dead after vsum)
    //   Vs    f16 [64 planes][8500][32] @ 34,816,000   (34,816,000)
    //   P     f16 [68000][384]          @ 69,632,000   (52,224,000)
    //   Wct   f16 [384][256]            @ 121,856,000  (196,608)
    //   Wvt   f16 [256][256]            @ 122,052,608  (131,072)
    //   Wot   f16 [256][256]            @ 122,183,680  (131,072)
    //   bcat  f32 [384]                 @ 122,314,752  (1,536)
    char* base = (char*)d_ws;
    unsigned short* Y    = (unsigned short*)base;
    unsigned short* O16  = (unsigned short*)base;            // alias (Y dead)
    unsigned short* Vs   = (unsigned short*)(base + 34816000);
    unsigned short* P    = (unsigned short*)(base + 69632000);
    unsigned short* Wct  = (unsigned short*)(base + 121856000);
    unsigned short* Wvt  = (unsigned short*)(base + 122052608);
    unsigned short* Wot  = (unsigned short*)(base + 122183680);
    float* bcat          = (float*)(base + 122314752);

    const int RT = (8 * LQ + 127) / 128;   // 532 row tiles

    // 0) weight prep
    prep_weights<<<dim3(898), 256, 0, stream>>>(Woff, boff, Watt, batt, Wval, Wout,
                                                Wct, Wvt, Wot, bcat);

    // 1) merged: Y = f16(inp @ Wval), P = f16(query @ Wcat + bcat)
    gemm_yp<<<dim3(RT, 5), 256, 0, stream>>>(inp, query, Wvt, Wct, bcat, Y, P);

    // 2) Vs planes = sum_{t2} Y + K(t1)*bval
    vsum_kernel<<<dim3((LQ * 4 + 255) / 256, 64), 256, 0, stream>>>(Y, bval, Vs);

    // 3) sampler -> O16 (aliases Y, dead after vsum)
    sample_kernel<<<dim3(((LQ + 15) / 16) * 8), 256, 0, stream>>>(P, refp, Vs, O16);

    // 4) d_out = O16 @ Wout + bout (fp32)
    gemm_out<<<dim3(RT, 2), 256, 0, stream>>>(O16, Wot, bout, out);
}